// Round 11
// baseline (3424.656 us; speedup 1.0000x reference)
//
#include <hip/hip_runtime.h>
#include <hip/hip_bf16.h>

typedef __hip_bfloat16 bf16;
using short8 = __attribute__((ext_vector_type(8))) short;
using f32x4  = __attribute__((ext_vector_type(4))) float;

__device__ __forceinline__ float b2f(bf16 v){ return __bfloat162float(v); }
__device__ __forceinline__ bf16  f2b(float v){ return __float2bfloat16(v); }

#define EPSV 1e-5f

// async global->LDS, 16B/lane, dest = wave-uniform base + lane*16
__device__ __forceinline__ void gload16(const void* g, void* l) {
  __builtin_amdgcn_global_load_lds(
      (const __attribute__((address_space(1))) unsigned int*)g,
      (__attribute__((address_space(3))) unsigned int*)l, 16, 0, 0);
}

// ===== fused f32 -> bf16 casts (qw,kw: 32768 f4; w2: 65536; c1: 32768) =====
__global__ __launch_bounds__(256) void k_cast4(
    const float* __restrict__ a, bf16* __restrict__ ao,
    const float* __restrict__ b, bf16* __restrict__ bo,
    const float* __restrict__ c, bf16* __restrict__ co,
    const float* __restrict__ d, bf16* __restrict__ dd) {
  int i = blockIdx.x * 256 + threadIdx.x;     // grid 640 -> 163840 exact
  const float* src; bf16* dst; int off;
  if (i < 32768)       { src = a; dst = ao; off = i; }
  else if (i < 65536)  { src = b; dst = bo; off = i - 32768; }
  else if (i < 131072) { src = c; dst = co; off = i - 65536; }
  else                 { src = d; dst = dd; off = i - 131072; }
  float4 v = ((const float4*)src)[off];
  union { ushort4 u; bf16 h[4]; } o;
  o.h[0] = f2b(v.x); o.h[1] = f2b(v.y); o.h[2] = f2b(v.z); o.h[3] = f2b(v.w);
  ((ushort4*)dst)[off] = o.u;
}

// ===== fused weight reshape for c2 (CI=512) and c3 (CI=2560) ==============
__global__ __launch_bounds__(256) void k_wtr2(
    const float* __restrict__ wa, bf16* __restrict__ wta,
    const float* __restrict__ wb, bf16* __restrict__ wtb) {
  int oc = blockIdx.x, yy = blockIdx.y;
  const float* w; bf16* wt; int CI, c0;
  if (yy < 4) { w = wa; wt = wta; CI = 512;  c0 = yy * 128; }
  else        { w = wb; wt = wtb; CI = 2560; c0 = (yy - 4) * 128; }
  __shared__ float ld[128 * 9];
  const float* src = w + ((size_t)oc * CI + c0) * 9;
  for (int i = threadIdx.x; i < 128 * 9; i += 256) ld[i] = src[i];
  __syncthreads();
  for (int i = threadIdx.x; i < 128 * 9; i += 256) {
    int k9 = i / 128, t = i - k9 * 128;
    wt[((size_t)k9 * 512 + oc) * CI + c0 + t] = f2b(ld[t * 9 + k9]);
  }
}

// ===== M1 NCHW f32 -> NHWC bf16 [4][64][64][2048] (fast path only) =========
__global__ __launch_bounds__(256) void k_m1t(const float* __restrict__ M1,
                                             bf16* __restrict__ M1b) {
  int b = blockIdx.x >> 6, y = blockIdx.x & 63;
  int c0 = blockIdx.y * 64;
  __shared__ float t[64][65];
  for (int i = threadIdx.x; i < 4096; i += 256) {
    int cc = i >> 6, x = i & 63;
    t[x][cc] = M1[((size_t)(b * 2048 + c0 + cc) * 64 + y) * 64 + x];
  }
  __syncthreads();
  for (int i = threadIdx.x; i < 4096; i += 256) {
    int x = i >> 6, cc = i & 63;
    M1b[((size_t)((b * 64 + y) * 64 + x)) * 2048 + c0 + cc] = f2b(t[x][cc]);
  }
}

// ===== F (NCHW f32) -> FP (b,p,n,c) bf16 via LDS transpose =================
__global__ __launch_bounds__(256) void k_fp2(const float* __restrict__ F,
                                             bf16* __restrict__ FP) {
  int b = blockIdx.x >> 6, y = blockIdx.x & 63;
  int tid = threadIdx.x;
  __shared__ float t[256][65];
  int p_hi = (y >> 3) << 3, n_hi = (y & 7) << 3;
  for (int half = 0; half < 2; half++) {
    int c0 = half << 8;
    for (int i = tid; i < 256 * 64; i += 256) {
      int cc = i >> 6, x = i & 63;
      t[cc][x] = F[((size_t)(b * 512 + c0 + cc) * 64 + y) * 64 + x];
    }
    __syncthreads();
    for (int x = 0; x < 64; x++) {
      int p = p_hi + (x >> 3), n = n_hi + (x & 7);
      FP[((size_t)(b * 64 + p)) * 32768 + n * 512 + c0 + tid] = f2b(t[tid][x]);
    }
    __syncthreads();
  }
}

// ===== softmax(I); FL0 = (bc*pix) @ FP  with FP slice in LDS ===============
__global__ __launch_bounds__(256) void k_flocal2(const float* __restrict__ I,
        const float* __restrict__ R, const bf16* __restrict__ FP,
        float* __restrict__ FL0) {
  int bp = blockIdx.x, b = bp >> 6, p = bp & 63;
  int tid = threadIdx.x, w = tid >> 6, lane = tid & 63;
  __shared__ __align__(16) bf16 fps[64 * 512];   // 64 KB
  __shared__ float pix[19][64];
  __shared__ float bc[19];
  {
    const bf16* src = FP + (size_t)bp * 32768 + lane * 8;
    #pragma unroll
    for (int t = 0; t < 16; t++) {
      int chunk = w + t * 4;
      gload16(src + chunk * 512, (char*)fps + chunk * 1024);
    }
  }
  int py = (p >> 3) * 8, px = (p & 7) * 8;
  for (int i = tid; i < 19 * 64; i += 256) {
    int k = i >> 6, n = i & 63;
    int y = py + (n >> 3), x = px + (n & 7);
    pix[k][n] = I[((size_t)(b * 19 + k) * 64 + y) * 64 + x];
  }
  if (tid < 19) bc[tid] = R[(size_t)(b * 19 + tid) * 64 + p];
  __syncthreads();
  if (tid < 19) {
    float mx = -1e30f;
    for (int n = 0; n < 64; n++) mx = fmaxf(mx, pix[tid][n]);
    float s = 0.f;
    for (int n = 0; n < 64; n++) { float e = __expf(pix[tid][n] - mx); pix[tid][n] = e; s += e; }
    float sc = bc[tid] / s;
    for (int n = 0; n < 64; n++) pix[tid][n] *= sc;
  }
  __syncthreads();
  for (int task = tid; task < 19 * 64; task += 256) {
    int k = task >> 6, c8 = (task & 63) << 3;
    float acc[8] = {};
    for (int n = 0; n < 64; n++) {
      float pv = pix[k][n];
      union { short8 s; bf16 h[8]; } v;
      v.s = *(const short8*)&fps[n * 512 + c8];
      #pragma unroll
      for (int j = 0; j < 8; j++) acc[j] += pv * b2f(v.h[j]);
    }
    float* dst = FL0 + ((size_t)(b * 64 + p) * 19 + k) * 512 + c8;
    #pragma unroll
    for (int j = 0; j < 8; j++) dst[j] = acc[j];
  }
}

// ===== LG part 1 (emits bf16 H) ============================================
__global__ __launch_bounds__(256) void k_lg1(const float* __restrict__ FL0,
        const float* __restrict__ w1, bf16* __restrict__ Hb) {
  int tid = threadIdx.x;
  int b = blockIdx.y;
  int n0 = blockIdx.x * 256;
  __shared__ float W[64][64];
  __shared__ float Xs[16][256];
  for (int i = tid; i < 4096; i += 256) W[i >> 6][i & 63] = w1[i];
  float acc[64];
  #pragma unroll
  for (int po = 0; po < 64; po++) acc[po] = 0.f;
  for (int q0 = 0; q0 < 64; q0 += 16) {
    __syncthreads();
    for (int i = tid; i < 4096; i += 256) {
      int q = i >> 8, j = i & 255;
      Xs[q][j] = FL0[(size_t)(b * 64 + q0 + q) * 9728 + n0 + j];
    }
    __syncthreads();
    for (int q = 0; q < 16; q++) {
      float xv = Xs[q][tid];
      #pragma unroll
      for (int po = 0; po < 64; po++) acc[po] += W[po][q0 + q] * xv;
    }
  }
  for (int po = 0; po < 64; po++) {
    float r = acc[po] + FL0[(size_t)(b * 64 + po) * 9728 + n0 + tid];
    Hb[(size_t)(b * 64 + po) * 9728 + n0 + tid] = f2b(fmaxf(r, 0.f));
  }
}

// ===== generic MFMA GEMM C[m][n] = sum_k A[m][k]*B[n][k] ===================
template<int MODE>
__global__ __launch_bounds__(256) void k_gmm(
    const bf16* __restrict__ A, const bf16* __restrict__ B,
    const float* __restrict__ bias, float* __restrict__ C,
    bf16* __restrict__ Cb, int N, int K,
    const float* __restrict__ g, const float* __restrict__ bb,
    const float* __restrict__ Fres, bf16* __restrict__ outb) {
  int tid = threadIdx.x;
  int m0 = blockIdx.x * 128, n0 = blockIdx.y * 128;
  int w = tid >> 6, lane = tid & 63, ln = lane & 15, qd = lane >> 4;
  int wm = w & 1, wn = w >> 1;
  __shared__ __align__(16) char smem[34816]; // staging 2x16KB | EP 128*136*2

  f32x4 acc[4][4];
  #pragma unroll
  for (int i = 0; i < 4; i++)
    #pragma unroll
    for (int j = 0; j < 4; j++) acc[i][j] = (f32x4){0.f, 0.f, 0.f, 0.f};

  int rsub = lane >> 2, ch = lane & 3;
  auto stage = [&](int p) {
    char* base = smem + (p & 1) * 16384;
    int k0 = p << 5;
    #pragma unroll
    for (int t = 0; t < 2; t++) {
      int ii = w + t * 4;
      int r = ii * 16 + rsub;
      int sw = (ch ^ ((r >> 1) & 3)) << 3;
      gload16(A + (size_t)(m0 + r) * K + k0 + sw, base + ii * 1024);
      gload16(B + (size_t)(n0 + r) * K + k0 + sw, base + 8192 + ii * 1024);
    }
  };
  auto compute = [&](int p) {
    const char* base = smem + (p & 1) * 16384;
    short8 af[4], bv[4];
    #pragma unroll
    for (int mi = 0; mi < 4; mi++) {
      int r = wm * 64 + mi * 16 + ln;
      af[mi] = *(const short8*)(base + r * 64 + ((qd ^ ((r >> 1) & 3)) << 4));
    }
    #pragma unroll
    for (int ni = 0; ni < 4; ni++) {
      int r = wn * 64 + ni * 16 + ln;
      bv[ni] = *(const short8*)(base + 8192 + r * 64 + ((qd ^ ((r >> 1) & 3)) << 4));
    }
    #pragma unroll
    for (int mi = 0; mi < 4; mi++)
      #pragma unroll
      for (int ni = 0; ni < 4; ni++)
        acc[mi][ni] = __builtin_amdgcn_mfma_f32_16x16x32_bf16(
            af[mi], bv[ni], acc[mi][ni], 0, 0, 0);
  };

  int KT = K >> 5;
  stage(0);
  __syncthreads();
  for (int p = 0; p < KT; p++) {
    if (p + 1 < KT) stage(p + 1);
    compute(p);
    __syncthreads();
  }

  if (MODE <= 1) {
    #pragma unroll
    for (int mi = 0; mi < 4; mi++) {
      #pragma unroll
      for (int r = 0; r < 4; r++) {
        int m = m0 + wm * 64 + mi * 16 + qd * 4 + r;
        #pragma unroll
        for (int ni = 0; ni < 4; ni++) {
          int n = n0 + wn * 64 + ni * 16 + ln;
          float v = acc[mi][ni][r];
          if (bias) v += bias[n];
          C[(size_t)m * N + n] = v;
          if (MODE == 1) Cb[(size_t)m * N + n] = f2b(v);
        }
      }
    }
  } else {
    bf16* EP = (bf16*)smem;  // [128 pix][136 oc-padded]
    int b = n0 >> 12;
    #pragma unroll
    for (int mi = 0; mi < 4; mi++) {
      #pragma unroll
      for (int r = 0; r < 4; r++) {
        int ml = wm * 64 + mi * 16 + qd * 4 + r;
        int oc = m0 + ml;
        float sc = g[oc] * rsqrtf(1.f + EPSV);
        float bt = bb[oc];
        #pragma unroll
        for (int ni = 0; ni < 4; ni++) {
          int nl = wn * 64 + ni * 16 + ln;
          int pix = n0 + nl;
          int y = (pix >> 6) & 63, x = pix & 63;
          float v = fmaxf(acc[mi][ni][r] * sc + bt, 0.f)
                  + Fres[((size_t)(b * 512 + oc) * 64 + y) * 64 + x];
          EP[nl * 136 + ml] = f2b(v);
        }
      }
    }
    __syncthreads();
    int pl = tid >> 1, half = tid & 1;
    size_t gb = (size_t)(n0 + pl) * 512 + m0 + half * 64;
    const bf16* row = &EP[pl * 136 + half * 64];
    #pragma unroll
    for (int j2 = 0; j2 < 8; j2++)
      *(short8*)(outb + gb + j2 * 8) = *(const short8*)(row + j2 * 8);
  }
}

// ===== fuse + value (float4 vw/fg) =========================================
__global__ __launch_bounds__(256) void k_fusev(const float* __restrict__ FL,
        const float* __restrict__ fw, const float* __restrict__ fbv,
        const float* __restrict__ vw, const float* __restrict__ vb,
        float* __restrict__ VAL) {
  int tid = threadIdx.x;
  int bk = blockIdx.x, b = bk / 19, k = bk % 19;
  __shared__ float fwl[64];
  __shared__ __align__(16) float fg[512];
  if (tid < 64) fwl[tid] = fw[tid];
  __syncthreads();
  float fbias = fbv[0];
  for (int c = tid; c < 512; c += 256) {
    float s = 0.f;
    for (int p = 0; p < 64; p++)
      s += fwl[p] * FL[((size_t)(b * 64 + p) * 19 + k) * 512 + c];
    fg[c] = s + fbias;
  }
  __syncthreads();
  int d = tid;
  float s = vb[d];
  const float4* vr = (const float4*)(vw + (size_t)d * 512);
  const float4* fr = (const float4*)fg;
  for (int c4 = 0; c4 < 128; c4++) {
    float4 wv = vr[c4], f = fr[c4];
    s += f.x * wv.x + f.y * wv.y + f.z * wv.z + f.w * wv.w;
  }
  VAL[(size_t)bk * 256 + d] = s;
}

// ===== per-patch attention -> FS NHWC bf16 (C=256), coalesced stores =======
__global__ __launch_bounds__(256) void k_attn(const float* __restrict__ Q,
        const float* __restrict__ KEY, const float* __restrict__ VAL,
        bf16* __restrict__ FS) {
  int tid = threadIdx.x;
  int bp = blockIdx.x, b = bp >> 6, p = bp & 63;
  __shared__ __align__(16) float ks[19][256];
  __shared__ __align__(16) float vs[19][256];
  __shared__ float Ss[64][20];
  __shared__ bf16 ot[64][256];
  for (int i = tid; i < 19 * 256; i += 256) {
    ks[i >> 8][i & 255] = KEY[(size_t)bp * 19 * 256 + i];
    vs[i >> 8][i & 255] = VAL[(size_t)b * 19 * 256 + i];
  }
  __syncthreads();
  {
    int n = tid >> 2, kq = tid & 3;
    const float4* qrow = (const float4*)(Q + ((size_t)bp * 64 + n) * 256);
    for (int k = kq; k < 19; k += 4) {
      const float4* kr = (const float4*)&ks[k][0];
      float s = 0.f;
      for (int d4 = 0; d4 < 64; d4++) {
        float4 qv = qrow[d4], kv = kr[d4];
        s += qv.x * kv.x + qv.y * kv.y + qv.z * kv.z + qv.w * kv.w;
      }
      Ss[n][k] = s;
    }
  }
  __syncthreads();
  if (tid < 64) {
    float mx = -1e30f;
    for (int k = 0; k < 19; k++) mx = fmaxf(mx, Ss[tid][k]);
    float sum = 0.f;
    for (int k = 0; k < 19; k++) { float e = __expf(Ss[tid][k] - mx); Ss[tid][k] = e; sum += e; }
    float inv = 1.f / sum;
    for (int k = 0; k < 19; k++) Ss[tid][k] *= inv;
  }
  __syncthreads();
  {
    int d = tid;
    for (int nn = 0; nn < 64; nn++) {
      float s = 0.f;
      #pragma unroll
      for (int k = 0; k < 19; k++) s += Ss[nn][k] * vs[k][d];
      ot[nn][d] = f2b(s);
    }
  }
  __syncthreads();
  {
    int py = (p >> 3) * 8, px = (p & 7) * 8;
    int nn = tid >> 2, q = tid & 3;
    int y = py + (nn >> 3), x = px + (nn & 7);
    size_t gb = (((size_t)(b * 64 + y) * 64) + x) * 256 + q * 64;
    const bf16* row = &ot[nn][q * 64];
    #pragma unroll
    for (int j = 0; j < 8; j++)
      *(short8*)(FS + gb + j * 8) = *(const short8*)(row + j * 8);
  }
}

// ===== MFMA conv3x3; A (weights) in REGISTERS (per-lane global loads), ====
// B in LDS.  8 waves (2ocg x 4y), wave = 64oc x 64x (4x4 frags of 16x16x32).
// A-frag: lane reads WT row oc0+wocg*64+mi*16+ln, elems c0+qd*8 (= MFMA A
// layout directly).  Aa/Ab register dbuf, prefetched 1 phase ahead
// (compiler-managed vmcnt).  One __syncthreads per c-group (drains B-gloads
// and protects B[2] dbuf).  LDS read traffic halves vs R9 (A off LDS pipe).
__global__ __launch_bounds__(512) void k_conv3(
    const bf16* __restrict__ Xin, int Cin,
    const bf16* __restrict__ M1b, const float* __restrict__ M1f, int C2,
    const bf16* __restrict__ WT,
    const float* __restrict__ g, const float* __restrict__ bb,
    bf16* __restrict__ out, int Cos) {
  int tid = threadIdx.x;
  int b = blockIdx.x >> 4, y0 = (blockIdx.x & 15) * 4;
  int oc0 = blockIdx.y * 128;
  int w = tid >> 6, lane = tid & 63, ln = lane & 15, qd = lane >> 4;
  int wocg = w & 1, wyp = w >> 1;      // wyp in 0..3 (y row)
  int Ct = Cin + C2;

  __shared__ __align__(16) char smem[66560];
  char* smB  = smem;                    // B[2][6][66][32] bf16 (2x25344)
  char* dump = smem + 65536;            // 1KB dummy sink (EP needs 65536)

  // zero halos in BOTH B buffers (stage never writes them)
  for (int bufi = 0; bufi < 2; bufi++) {
    char* bbuf = smB + bufi * 25344;
    for (int i = tid; i < 6 * 2 * 32; i += 512) {
      int rl = i >> 6, hh = (i >> 5) & 1, kk = i & 31;
      *(bf16*)(bbuf + (rl * 66 + (hh ? 65 : 0)) * 64 + kk * 2) = f2b(0.f);
    }
    if (y0 == 0)
      for (int i = tid; i < 66 * 16; i += 512) ((float*)bbuf)[i] = 0.f;
    if (y0 == 60)
      for (int i = tid; i < 66 * 16; i += 512)
        ((float*)(bbuf + 5 * 66 * 64))[i] = 0.f;
  }

  f32x4 acc[4][4];
  #pragma unroll
  for (int i = 0; i < 4; i++)
    #pragma unroll
    for (int j = 0; j < 4; j++) acc[i][j] = (f32x4){0.f, 0.f, 0.f, 0.f};

  int ngroups = Ct >> 5;   // 16 (Ct=512) or 80 (Ct=2560); always even

  // per-lane constant part of the A address (elements)
  const bf16* Alane = WT + (size_t)(oc0 + wocg * 64 + ln) * Ct + qd * 8;

  auto stageB = [&](int gi) {  // fast path: exactly 3 gload16 per wave
    int c0 = gi << 5;
    char* bbuf = smB + (gi & 1) * 25344;
    if (c0 < Cin || M1b != nullptr) {
      const bf16* T; int Cs, cb;
      if (c0 < Cin) { T = Xin; Cs = Cin; cb = c0; }
      else          { T = M1b; Cs = C2;  cb = c0 - Cin; }
      #pragma unroll
      for (int t = 0; t < 3; t++) {
        int j = w + t * 8;               // 0..23
        int rl = j >> 2, q = j & 3;
        int yy = y0 + rl - 1;
        bool ok = (unsigned)yy < 64u;
        int yc = ok ? yy : y0;
        int xx = q * 16 + (lane >> 2), xr = xx + 1;
        const bf16* src = T + ((size_t)((b * 64 + yc) * 64 + xx) * Cs + cb)
                        + (((lane & 3) ^ ((xr >> 1) & 3)) << 3);
        char* dst = ok ? (bbuf + (rl * 66 + 1 + q * 16) * 64) : dump;
        gload16(src, dst);
      }
    } else {
      // slow fallback: transpose M1 f32 NCHW in-register (ws too small)
      if (w < 6) {
        int rl = w, yy = y0 + rl - 1;
        if ((unsigned)yy < 64u) {
          int xx = lane, xr = xx + 1;
          const float* mp = M1f + ((size_t)(b * 2048 + (c0 - Cin)) * 64 + yy) * 64 + xx;
          #pragma unroll
          for (int q = 0; q < 8; q++) {
            union { ushort4 u; bf16 h[4]; } pk;
            #pragma unroll
            for (int jj = 0; jj < 4; jj++) pk.h[jj] = f2b(mp[(size_t)(q * 4 + jj) * 4096]);
            *(ushort4*)(bbuf + (rl * 66 + xr) * 64
                        + ((((q >> 1) ^ ((xr >> 1) & 3)) << 4) | ((q & 1) << 3))) = pk.u;
          }
        }
      }
    }
  };
  auto loadA = [&](short8* dst, int ky, int c0) {   // 12 per-lane 16B loads
    #pragma unroll
    for (int kx = 0; kx < 3; kx++)
      #pragma unroll
      for (int mi = 0; mi < 4; mi++)
        dst[kx * 4 + mi] = *(const short8*)(Alane
            + (size_t)((ky * 3 + kx) * 512 + mi * 16) * Ct + c0);
  };
  auto computeP = [&](const short8* A, int ky, int gpar) {
    const char* bB = smB + gpar * 25344;
    int rl = wyp + ky;                    // 0..5
    #pragma unroll
    for (int kx = 0; kx < 3; kx++) {
      short8 bv[4];
      #pragma unroll
      for (int ni = 0; ni < 4; ni++) {
        int xr = ni * 16 + ln + kx;
        bv[ni] = *(const short8*)(bB + (rl * 66 + xr) * 64
                                  + ((qd ^ ((xr >> 1) & 3)) << 4));
      }
      #pragma unroll
      for (int mi = 0; mi < 4; mi++)
        #pragma unroll
        for (int ni = 0; ni < 4; ni++)
          acc[mi][ni] = __builtin_amdgcn_mfma_f32_16x16x32_bf16(
              A[kx * 4 + mi], bv[ni], acc[mi][ni], 0, 0, 0);
    }
  };

  short8 Aa[12], Ab[12];
  // prologue: stage B(0); load A(group0, ky0); barrier drains everything.
  stageB(0);
  loadA(Aa, 0, 0);
  __syncthreads();

  for (int gi = 0; gi < ngroups; gi += 2) {
    int c0 = gi << 5, c1 = c0 + 32, c2 = c0 + 64;
    bool hb1 = gi + 1 < ngroups;   // always true (ngroups even), kept for safety
    bool hb2 = gi + 2 < ngroups;
    // ---- group gi (reads B[0]) ----
    loadA(Ab, 1, c0);
    computeP(Aa, 0, 0);
    loadA(Aa, 2, c0);
    if (hb1) stageB(gi + 1);
    computeP(Ab, 1, 0);
    if (hb1) loadA(Ab, 0, c1);
    computeP(Aa, 2, 0);
    __syncthreads();   // B[1] ready; all done reading B[0]
    if (!hb1) break;
    // ---- group gi+1 (reads B[1]) ----
    loadA(Aa, 1, c1);
    computeP(Ab, 0, 1);
    loadA(Ab, 2, c1);
    if (hb2) stageB(gi + 2);
    computeP(Aa, 1, 1);
    if (hb2) loadA(Aa, 0, c2);
    computeP(Ab, 2, 1);
    __syncthreads();   // B[0] ready; all done reading B[1]
  }

  // epilogue: BN+ReLU, LDS transpose -> coalesced NHWC stores
  {
    bf16* EP = (bf16*)smem;   // [4y][64x][128 ocl] = 64 KB
    #pragma unroll
    for (int mi = 0; mi < 4; mi++) {
      int oclb = wocg * 64 + mi * 16 + qd * 4;
      float sc[4], bt[4];
      #pragma unroll
      for (int r = 0; r < 4; r++) {
        int oc = oc0 + oclb + r;
        sc[r] = g[oc] * rsqrtf(1.f + EPSV);
        bt[r] = bb[oc];
      }
      #pragma unroll
      for (int ni = 0; ni < 4; ni++) {
        int x = ni * 16 + ln;
        union { ushort4 u; bf16 h[4]; } pk;
        #pragma unroll
        for (int r = 0; r < 4; r++)
          pk.h[r] = f2b(fmaxf(acc[mi][ni][r] * sc[r] + bt[r], 0.f));
        *(ushort4*)&EP[(wyp * 64 + x) * 128 + oclb] = pk.u;
      }
    }
    __syncthreads();
    int pixl = tid >> 1, hh = tid & 1;
    int yloc = pixl >> 6, x = pixl & 63;
    size_t gb = ((size_t)((b * 64 + y0 + yloc) * 64 + x)) * Cos + oc0 + hh * 64;
    const bf16* row = &EP[pixl * 128 + hh * 64];
    #pragma unroll
    for (int k = 0; k < 8; k++)
      *(short8*)(out + gb + k * 8) = *(const short8*)(row + k * 8);
  }
}

// ===== final 1x1 (512->19) from NHWC X3 ====================================
__global__ __launch_bounds__(256) void k_final(const bf16* __restrict__ X3,
        const float* __restrict__ dw, float* __restrict__ out) {
  int tid = threadIdx.x;
  int b = blockIdx.x >> 6, y = blockIdx.x & 63;
  __shared__ float W[19 * 512];
  for (int i = tid; i < 19 * 512; i += 256) W[i] = dw[i];
  __syncthreads();
  int x = tid & 63, kg = tid >> 6;
  const bf16* px = X3 + (((size_t)(b * 64 + y) * 64) + x) * 512;
  float acc[5] = {0.f, 0.f, 0.f, 0.f, 0.f};
  for (int c8 = 0; c8 < 512; c8 += 8) {
    union { short8 s; bf16 h[8]; } v;
    v.s = *(const short8*)(px + c8);
    float f[8];
    #pragma unroll
    for (int j = 0; j < 8; j++) f[j] = b2f(v.h[j]);
    #pragma unroll
    for (int i = 0; i < 5; i++) {
      int k = kg * 5 + i;
      if (k < 19) {
        const float* wr = &W[k * 512 + c8];
        #pragma unroll
        for (int j = 0; j < 8; j++) acc[i] += f[j] * wr[j];
      }
    }
  }
  for (int i = 0; i < 5; i++) {
    int k = kg * 5 + i;
    if (k < 19) out[((size_t)(b * 19 + k) * 64 + y) * 64 + x] = acc[i];
  }
}

extern "C" void kernel_launch(void* const* d_in, const int* in_sizes, int n_in,
                              void* d_out, int out_size, void* d_ws, size_t ws_size,
                              hipStream_t stream) {
  (void)in_sizes; (void)n_in; (void)out_size;
  const float* M1 = (const float*)d_in[0];
  const float* F  = (const float*)d_in[1];
  const float* Iin= (const float*)d_in[2];
  const float* R  = (const float*)d_in[3];
  const float* w1 = (const float*)d_in[4];
  const float* w2 = (const float*)d_in[5];
  const float* fw = (const float*)d_in[6];
  const float* fb = (const float*)d_in[7];
  const float* qw = (const float*)d_in[8];
  const float* qb = (const float*)d_in[9];
  const float* kw = (const float*)d_in[10];
  const float* kb = (const float*)d_in[11];
  const float* vw = (const float*)d_in[12];
  const float* vb = (const float*)d_in[13];
  const float* c1 = (const float*)d_in[14];
  const float* g1 = (const float*)d_in[15];
  const float* b1 = (const float*)d_in[16];
  const float* c2 = (const float*)d_in[17];
  const float* g2 = (const float*)d_in[18];
  const float* b2 = (const float*)d_in[19];
  const float* c3 = (const float*)d_in[20];
  const float* g3 = (const float*)d_in[21];
  const float* b3 = (const float*)d_in[22];
  const float* dw = (const float*)d_in[23];

  char* ws = (char*)d_ws;
  bool fast = ws_size >= (size_t)137363456ULL;

  bf16*  qwb  = (bf16*)(ws + 0);           //   262,144
  bf16*  kwb  = (bf16*)(ws + 262144);      //   262,144
  bf16*  w2b  = (bf16*)(ws + 524288);      //   524,288
  bf16*  c1b  = (bf16*)(ws + 1048576);     //   262,144
  bf16*  WT2  = (bf16*)(ws + 0);           //  4,718,592 (after conv1)
  bf16*  WT3  = (bf16*)(ws + 4718592);     // 23,592,960
  bf16*  FS   = (bf16*)(ws + 28311552);    //  8,388,608  NHWC (C=256)
  bf16*  FO1  = (bf16*)(ws + 36700160);    // 16,777,216  NHWC (C=512)
  bf16*  X2   = (bf16*)(ws + 53477376);    // 16,777,216  NHWC (C=512)
  bf16*  M1bf = fast ? (bf16*)(ws + 70254592) : nullptr;  // 67,108,864 NHWC
  bf16*  X3   = (bf16*)(ws + 28311552);    // overlay FS+FO1 (dead by then)
  bf16*  FP    = (bf16*) (ws + 53477376);  // X2 region
  float* QUERY = (float*)(ws + 70254592);  // 16,777,216
  float* FL0   = (float*)(ws + 87031808);  //  9,961,472
  bf16*  Hb    = (bf16*) (ws + 96993280);  //  4,980,736
  bf16*  FLb   = (bf16*) (ws + 101974016); //  4,980,736
  float* KEY   = (float*)(ws + 106954752); //  4,980,736
  float* VAL   = (float*)(ws + 111935488); //     77,824
  float* FL    = FL0;

  k_cast4<<<640, 256, 0, stream>>>(qw, qwb, kw, kwb, w2, w2b, c1, c1b);
  k_fp2<<<256, 256, 0, stream>>>(F, FP);
  k_flocal2<<<256, 256, 0, stream>>>(Iin, R, FP, FL0);
  k_lg1<<<dim3(38, 4), 256, 0, stream>>>(FL0, w1, Hb);
  k_gmm<1><<<dim3(38, 4), 256, 0, stream>>>(Hb, w2b, nullptr, FL, FLb, 512, 512,
                                            nullptr, nullptr, nullptr, nullptr);
  k_fusev<<<76, 256, 0, stream>>>(FL, fw, fb, vw, vb, VAL);
  k_gmm<0><<<dim3(38, 2), 256, 0, stream>>>(FLb, kwb, kb, KEY, nullptr, 256, 512,
                                            nullptr, nullptr, nullptr, nullptr);
  k_gmm<0><<<dim3(128, 2), 256, 0, stream>>>(FP, qwb, qb, QUERY, nullptr, 256, 512,
                                             nullptr, nullptr, nullptr, nullptr);
  k_attn<<<256, 256, 0, stream>>>(QUERY, KEY, VAL, FS);
  if (fast) k_m1t<<<dim3(256, 32), 256, 0, stream>>>(M1, M1bf);
  k_gmm<2><<<dim3(4, 128), 256, 0, stream>>>(c1b, FS, nullptr, nullptr, nullptr,
                                             16384, 256, g1, b1, F, FO1);
  k_wtr2<<<dim3(512, 24), 256, 0, stream>>>(c2, WT2, c3, WT3);
  k_conv3<<<dim3(64, 4), 512, 0, stream>>>(FO1, 512, nullptr, nullptr, 0,
                                           WT2, g2, b2, X2, 512);
  k_conv3<<<dim3(64, 4), 512, 0, stream>>>(X2, 512, M1bf, M1, 2048,
                                           WT3, g3, b3, X3, 512);
  k_final<<<256, 256, 0, stream>>>(X3, dw, (float*)d_out);
}